// Round 5
// baseline (313.209 us; speedup 1.0000x reference)
//
#include <hip/hip_runtime.h>
#include <hip/hip_cooperative_groups.h>

namespace cg = cooperative_groups;

#define BB 8
#define TT 1024
#define FF 512
#define DD 64
#define LCH 16
#define CCH (TT / LCH)
#define EE (DD * DD)

__device__ __forceinline__ float wave_sum64(float v) {
  #pragma unroll
  for (int m = 32; m >= 1; m >>= 1) v += __shfl_xor(v, m, 64);
  return v;
}

// One cooperative kernel: block = one 16-token chunk.
//  Phase 1: stage x -> LN -> KQV projection (f-split, 2-half partial reduce)
//           -> K/Q/V stay in LDS -> chunk outer-sum S -> global S (1 MB only)
//  grid.sync()
//  Phase 2: prefix base for this chunk summed from predecessor S tiles (regs)
//  Phase 3: in-chunk scan, nontemporal state_seq stores, y via LDS reduce.
// LDS: 36 KB (4 blocks/CU capacity; co-residency needs only 2/CU for grid=512).
__global__ __launch_bounds__(256) void fused_k(
    const float* __restrict__ x, const float* __restrict__ st0,
    const float* __restrict__ Wk, const float* __restrict__ Wq,
    const float* __restrict__ Wv,
    const float* __restrict__ gamma, const float* __restrict__ beta,
    float* __restrict__ S, float* __restrict__ y, float* __restrict__ sseq) {
  __shared__ float smem[9216];       // 36 KB
  float* lx   = smem;                // [16][512] phases A-C
  float* part = smem;                // [4][8][3][64] = 6144 floats, after C
  float* lk   = smem + 6144;         // [16][64]
  float* lq   = smem + 7168;         // [16][64]
  float* lv   = smem + 8192;         // [16][64]
  // yp = smem[0..4095] in phase 3 (part region dead by then)

  const int tid = threadIdx.x;
  const int wv = tid >> 6, lane = tid & 63;
  const int bc = blockIdx.x;
  const int b = bc >> 6, c = bc & (CCH - 1);
  const size_t row0 = (size_t)bc * LCH;

  { // A: stage 16 x-rows (32 KB), coalesced float4
    const float4* xg = (const float4*)(x + row0 * FF);
    float4* lx4 = (float4*)lx;
    #pragma unroll
    for (int i = 0; i < 8; ++i)
      lx4[tid + 256 * i] = xg[tid + 256 * i];
  }
  __syncthreads();

  { // B: LayerNorm in LDS, 4 rows per wave
    float g[8], bt[8];
    #pragma unroll
    for (int k = 0; k < 8; ++k) {
      g[k]  = gamma[lane + 64 * k];
      bt[k] = beta[lane + 64 * k];
    }
    #pragma unroll
    for (int rr = 0; rr < 4; ++rr) {
      int r = wv * 4 + rr;
      float v[8];
      float s = 0.f, ss = 0.f;
      #pragma unroll
      for (int k = 0; k < 8; ++k) {
        v[k] = lx[r * FF + lane + 64 * k];
        s += v[k]; ss += v[k] * v[k];
      }
      s = wave_sum64(s); ss = wave_sum64(ss);
      float m = s * (1.f / FF);
      float var = ss * (1.f / FF) - m * m;
      float rs = rsqrtf(var + 1e-5f);
      #pragma unroll
      for (int k = 0; k < 8; ++k)
        lx[r * FF + lane + 64 * k] = (v[k] - m) * rs * g[k] + bt[k];
    }
  }
  __syncthreads();

  // C: partial dots over this wave's 128-wide f-chunk, 16 rows x 3 proj
  float acc[LCH][3];
  #pragma unroll
  for (int r = 0; r < LCH; ++r)
    #pragma unroll
    for (int p = 0; p < 3; ++p) acc[r][p] = 0.f;

  const int fbase = wv * (FF / 4);
  #pragma unroll 2
  for (int f0 = fbase; f0 < fbase + FF / 4; f0 += 4) {
    float wk0 = Wk[(f0 + 0) * DD + lane], wk1 = Wk[(f0 + 1) * DD + lane];
    float wk2 = Wk[(f0 + 2) * DD + lane], wk3 = Wk[(f0 + 3) * DD + lane];
    float wq0 = Wq[(f0 + 0) * DD + lane], wq1 = Wq[(f0 + 1) * DD + lane];
    float wq2 = Wq[(f0 + 2) * DD + lane], wq3 = Wq[(f0 + 3) * DD + lane];
    float wv0 = Wv[(f0 + 0) * DD + lane], wv1 = Wv[(f0 + 1) * DD + lane];
    float wv2 = Wv[(f0 + 2) * DD + lane], wv3 = Wv[(f0 + 3) * DD + lane];
    #pragma unroll
    for (int r = 0; r < LCH; ++r) {
      float4 xv = *(const float4*)&lx[r * FF + f0];
      acc[r][0] += (xv.x * wk0 + xv.y * wk1) + (xv.z * wk2 + xv.w * wk3);
      acc[r][1] += (xv.x * wq0 + xv.y * wq1) + (xv.z * wq2 + xv.w * wq3);
      acc[r][2] += (xv.x * wv0 + xv.y * wv1) + (xv.z * wv2 + xv.w * wv3);
    }
  }
  __syncthreads();   // all lx reads done; part overlays lx region

  // D/E in two row-halves (24 KB part buffer folded into lx region)
  #pragma unroll
  for (int h = 0; h < 2; ++h) {
    #pragma unroll
    for (int r = 0; r < 8; ++r)
      #pragma unroll
      for (int p = 0; p < 3; ++p)
        part[((wv * 8 + r) * 3 + p) * DD + lane] = acc[h * 8 + r][p];
    __syncthreads();
    #pragma unroll
    for (int i = 0; i < 6; ++i) {   // 24 (row,proj) pairs, 6 per wave
      int pid = wv * 6 + i;
      int r = pid / 3, p = pid - r * 3;
      float val = part[((0 * 8 + r) * 3 + p) * DD + lane]
                + part[((1 * 8 + r) * 3 + p) * DD + lane]
                + part[((2 * 8 + r) * 3 + p) * DD + lane]
                + part[((3 * 8 + r) * 3 + p) * DD + lane];
      if (p < 2) {
        val = fmaxf(val, 0.f);
        float sm = wave_sum64(val);
        val = val / (1e-5f + sm);
      }
      int rg = h * 8 + r;
      if (p == 0)      lk[rg * DD + lane] = val;
      else if (p == 1) lq[rg * DD + lane] = val;
      else             lv[rg * DD + lane] = val;
    }
    __syncthreads();
  }

  // F: chunk outer-product sum -> global S (the only phase-1 global write)
  {
    const int j = lane, s0 = wv << 4;
    float a2[16];
    #pragma unroll
    for (int ii = 0; ii < 16; ++ii) a2[ii] = 0.f;
    #pragma unroll
    for (int t = 0; t < LCH; ++t) {
      float kj = lk[t * DD + j];
      #pragma unroll
      for (int ii = 0; ii < 16; ++ii) a2[ii] += lv[t * DD + s0 + ii] * kj;
    }
    float* Sp = S + (size_t)bc * EE;
    #pragma unroll
    for (int ii = 0; ii < 16; ++ii) Sp[(s0 + ii) * DD + j] = a2[ii];
  }

  __threadfence();          // device-scope: make S visible across XCDs
  cg::this_grid().sync();

  // Phase 2: exclusive-prefix base for this chunk, entirely in registers.
  const int i0 = wv << 4;
  float run[16];
  {
    const float* s0p = st0 + (size_t)b * EE;
    #pragma unroll
    for (int ii = 0; ii < 16; ++ii) run[ii] = s0p[(i0 + ii) * DD + lane];
    const float* Sb = S + (size_t)b * CCH * EE;
    for (int cc = 0; cc < c; ++cc) {
      const float* Sc = Sb + (size_t)cc * EE;
      #pragma unroll
      for (int ii = 0; ii < 16; ++ii) run[ii] += Sc[(i0 + ii) * DD + lane];
    }
  }

  // Phase 3: in-chunk scan + y (K/Q/V hot in LDS; state_seq nontemporal)
  float* yp = smem;   // [4][16][64], overlays dead part/lx region
  {
    const int j = lane;
    float* so = sseq + (size_t)bc * LCH * EE + (size_t)i0 * DD + j;
    for (int t = 0; t < LCH; ++t) {
      float kj = lk[t * DD + j];
      float* sot = so + (size_t)t * EE;
      float y0 = 0.f, y1 = 0.f, y2 = 0.f, y3 = 0.f;
      #pragma unroll
      for (int q4 = 0; q4 < 4; ++q4) {
        float4 vt = *(const float4*)&lv[t * DD + i0 + q4 * 4];
        float4 qt = *(const float4*)&lq[t * DD + i0 + q4 * 4];
        run[q4*4+0] += vt.x * kj; __builtin_nontemporal_store(run[q4*4+0], &sot[(q4*4+0) * DD]); y0 += run[q4*4+0] * qt.x;
        run[q4*4+1] += vt.y * kj; __builtin_nontemporal_store(run[q4*4+1], &sot[(q4*4+1) * DD]); y1 += run[q4*4+1] * qt.y;
        run[q4*4+2] += vt.z * kj; __builtin_nontemporal_store(run[q4*4+2], &sot[(q4*4+2) * DD]); y2 += run[q4*4+2] * qt.z;
        run[q4*4+3] += vt.w * kj; __builtin_nontemporal_store(run[q4*4+3], &sot[(q4*4+3) * DD]); y3 += run[q4*4+3] * qt.w;
      }
      yp[(wv * LCH + t) * DD + j] = (y0 + y1) + (y2 + y3);
    }
  }
  __syncthreads();
  {
    float* yo = y + (size_t)bc * LCH * DD;
    #pragma unroll
    for (int tt = 0; tt < 4; ++tt) {
      int t = wv * 4 + tt;
      yo[t * DD + lane] = (yp[(0 * LCH + t) * DD + lane] + yp[(1 * LCH + t) * DD + lane])
                        + (yp[(2 * LCH + t) * DD + lane] + yp[(3 * LCH + t) * DD + lane]);
    }
  }
}

extern "C" void kernel_launch(void* const* d_in, const int* in_sizes, int n_in,
                              void* d_out, int out_size, void* d_ws, size_t ws_size,
                              hipStream_t stream) {
  const float* x     = (const float*)d_in[0];
  const float* st0   = (const float*)d_in[1];
  const float* Wk    = (const float*)d_in[2];
  const float* Wq    = (const float*)d_in[3];
  const float* Wv    = (const float*)d_in[4];
  const float* gamma = (const float*)d_in[5];
  const float* beta  = (const float*)d_in[6];

  float* out  = (float*)d_out;                    // fp32 — reference dtype!
  float* yout = out;                              // y [B,T,D] first
  float* sseq = out + (size_t)BB * TT * DD;       // state_seq [B,T,D,D]

  float* Sbuf = (float*)d_ws;                     // only workspace user: 1 MB

  void* args[] = {(void*)&x, (void*)&st0, (void*)&Wk, (void*)&Wq, (void*)&Wv,
                  (void*)&gamma, (void*)&beta, (void*)&Sbuf, (void*)&yout,
                  (void*)&sseq};
  hipLaunchCooperativeKernel((void*)fused_k, dim3(BB * CCH), dim3(256),
                             args, 0, stream);
}

// Round 6
// 215.452 us; speedup vs baseline: 1.4537x; 1.4537x over previous
//
#include <hip/hip_runtime.h>

#define BB 8
#define TT 1024
#define FF 512
#define DD 64
#define LCH 16
#define CCH (TT / LCH)
#define SEG 8             // chunks per prefix segment
#define NSEG (CCH / SEG)  // 8 segments per batch
#define EE (DD * DD)

__device__ __forceinline__ float wave_sum64(float v) {
  #pragma unroll
  for (int m = 32; m >= 1; m >>= 1) v += __shfl_xor(v, m, 64);
  return v;
}

// ------- Kernel 1: LN + KQV projection + chunk outer sum, 36 KB LDS -----
// Block = one 16-token chunk, 256 thr. Two-half partial reduce (validated
// in the fused experiment) keeps LDS at 36 KB -> 2+ co-resident blocks/CU.
__global__ __launch_bounds__(256) void lnprojcs_k(
    const float* __restrict__ x,
    const float* __restrict__ gamma, const float* __restrict__ beta,
    const float* __restrict__ Wk, const float* __restrict__ Wq,
    const float* __restrict__ Wv,
    float* __restrict__ Ko, float* __restrict__ Qo, float* __restrict__ Vo,
    float* __restrict__ S) {
  __shared__ float smem[9216];       // 36 KB
  float* lx   = smem;                // [16][512] during A-C (32 KB)
  float* part = smem;                // [4][8][3][64] = 6144 floats, after C
  float* lk   = smem + 6144;         // [16][64]
  float* lv   = smem + 7168;         // [16][64]

  const int tid = threadIdx.x;
  const int wv = tid >> 6, lane = tid & 63;
  const int bc = blockIdx.x;
  const size_t row0 = (size_t)bc * LCH;

  { // A: stage 16 x-rows, coalesced float4
    const float4* xg = (const float4*)(x + row0 * FF);
    float4* lx4 = (float4*)lx;
    #pragma unroll
    for (int i = 0; i < 8; ++i)
      lx4[tid + 256 * i] = xg[tid + 256 * i];
  }
  __syncthreads();

  { // B: LayerNorm in LDS, 4 rows per wave
    float g[8], bt[8];
    #pragma unroll
    for (int k = 0; k < 8; ++k) {
      g[k]  = gamma[lane + 64 * k];
      bt[k] = beta[lane + 64 * k];
    }
    #pragma unroll
    for (int rr = 0; rr < 4; ++rr) {
      int r = wv * 4 + rr;
      float v[8];
      float s = 0.f, ss = 0.f;
      #pragma unroll
      for (int k = 0; k < 8; ++k) {
        v[k] = lx[r * FF + lane + 64 * k];
        s += v[k]; ss += v[k] * v[k];
      }
      s = wave_sum64(s); ss = wave_sum64(ss);
      float m = s * (1.f / FF);
      float var = ss * (1.f / FF) - m * m;
      float rs = rsqrtf(var + 1e-5f);
      #pragma unroll
      for (int k = 0; k < 8; ++k)
        lx[r * FF + lane + 64 * k] = (v[k] - m) * rs * g[k] + bt[k];
    }
  }
  __syncthreads();

  // C: partial dots over this wave's 128-wide f-chunk, 16 rows x 3 proj
  float acc[LCH][3];
  #pragma unroll
  for (int r = 0; r < LCH; ++r)
    #pragma unroll
    for (int p = 0; p < 3; ++p) acc[r][p] = 0.f;

  const int fbase = wv * (FF / 4);
  #pragma unroll 2
  for (int f0 = fbase; f0 < fbase + FF / 4; f0 += 4) {
    float wk0 = Wk[(f0 + 0) * DD + lane], wk1 = Wk[(f0 + 1) * DD + lane];
    float wk2 = Wk[(f0 + 2) * DD + lane], wk3 = Wk[(f0 + 3) * DD + lane];
    float wq0 = Wq[(f0 + 0) * DD + lane], wq1 = Wq[(f0 + 1) * DD + lane];
    float wq2 = Wq[(f0 + 2) * DD + lane], wq3 = Wq[(f0 + 3) * DD + lane];
    float wv0 = Wv[(f0 + 0) * DD + lane], wv1 = Wv[(f0 + 1) * DD + lane];
    float wv2 = Wv[(f0 + 2) * DD + lane], wv3 = Wv[(f0 + 3) * DD + lane];
    #pragma unroll
    for (int r = 0; r < LCH; ++r) {
      float4 xv = *(const float4*)&lx[r * FF + f0];
      acc[r][0] += (xv.x * wk0 + xv.y * wk1) + (xv.z * wk2 + xv.w * wk3);
      acc[r][1] += (xv.x * wq0 + xv.y * wq1) + (xv.z * wq2 + xv.w * wq3);
      acc[r][2] += (xv.x * wv0 + xv.y * wv1) + (xv.z * wv2 + xv.w * wv3);
    }
  }
  __syncthreads();   // lx dead; part/lk/lv overlay it

  // D/E in two row-halves; store K/Q/V to global, K & V also to LDS
  #pragma unroll
  for (int h = 0; h < 2; ++h) {
    #pragma unroll
    for (int r = 0; r < 8; ++r)
      #pragma unroll
      for (int p = 0; p < 3; ++p)
        part[((wv * 8 + r) * 3 + p) * DD + lane] = acc[h * 8 + r][p];
    __syncthreads();
    #pragma unroll
    for (int i = 0; i < 6; ++i) {   // 24 (row,proj) pairs, 6 per wave
      int pid = wv * 6 + i;
      int r = pid / 3, p = pid - r * 3;
      float val = part[((0 * 8 + r) * 3 + p) * DD + lane]
                + part[((1 * 8 + r) * 3 + p) * DD + lane]
                + part[((2 * 8 + r) * 3 + p) * DD + lane]
                + part[((3 * 8 + r) * 3 + p) * DD + lane];
      if (p < 2) {
        val = fmaxf(val, 0.f);
        float sm = wave_sum64(val);
        val = val / (1e-5f + sm);
      }
      int rg = h * 8 + r;
      float* outp = (p == 0) ? Ko : (p == 1) ? Qo : Vo;
      outp[(row0 + rg) * DD + lane] = val;
      if (p == 0)      lk[rg * DD + lane] = val;
      else if (p == 2) lv[rg * DD + lane] = val;
    }
    __syncthreads();
  }

  // F: chunk outer-product sum -> S
  {
    const int j = lane, s0 = wv << 4;
    float a2[16];
    #pragma unroll
    for (int ii = 0; ii < 16; ++ii) a2[ii] = 0.f;
    #pragma unroll
    for (int t = 0; t < LCH; ++t) {
      float kj = lk[t * DD + j];
      #pragma unroll
      for (int ii = 0; ii < 16; ++ii) a2[ii] += lv[t * DD + s0 + ii] * kj;
    }
    float* Sp = S + (size_t)bc * EE;
    #pragma unroll
    for (int ii = 0; ii < 16; ++ii) Sp[(s0 + ii) * DD + j] = a2[ii];
  }
}

// ------- Kernel 2: segment sums Z[b][seg] = sum of 8 chunk S tiles ------
__global__ __launch_bounds__(256) void segsum_k(const float* __restrict__ S,
                                                float* __restrict__ Z) {
  int blk = blockIdx.x;
  int b = blk >> 7;
  int seg = (blk >> 4) & 7;
  int e = ((blk & 15) << 8) + threadIdx.x;
  const float* Sb = S + ((size_t)(b * CCH + seg * SEG)) * EE + e;
  float sv[SEG];
  #pragma unroll
  for (int c = 0; c < SEG; ++c) sv[c] = Sb[(size_t)c * EE];
  float acc = 0.f;
  #pragma unroll
  for (int c = 0; c < SEG; ++c) acc += sv[c];
  Z[((size_t)(b * NSEG + seg)) * EE + e] = acc;
}

// ------- Kernel 3: prefix base (from Z + in-seg S) + in-chunk scan ------
// No P array: each block rebuilds its exclusive-prefix base from
// st0 + <=7 Z tiles + <=7 S tiles (independent, L2-resident reads).
__global__ __launch_bounds__(256) void scan_k(const float* __restrict__ Kx,
                     const float* __restrict__ Qx, const float* __restrict__ Vx,
                     const float* __restrict__ S, const float* __restrict__ Z,
                     const float* __restrict__ st0,
                     float* __restrict__ y, float* __restrict__ sout) {
  int bc = blockIdx.x, tid = threadIdx.x;
  int wv = tid >> 6, j = tid & 63;
  int i0 = wv * 16;
  int b = bc >> 6, c = bc & (CCH - 1);
  int seg = c >> 3, cin = c & 7;
  __shared__ float yp[4][LCH][DD];   // 16 KB

  // prefix base
  float run[16];
  {
    const float* s0p = st0 + (size_t)b * EE;
    #pragma unroll
    for (int ii = 0; ii < 16; ++ii) run[ii] = s0p[(i0 + ii) * DD + j];
    const float* Zb = Z + (size_t)b * NSEG * EE;
    for (int s = 0; s < seg; ++s) {
      const float* Zs = Zb + (size_t)s * EE;
      #pragma unroll
      for (int ii = 0; ii < 16; ++ii) run[ii] += Zs[(i0 + ii) * DD + j];
    }
    const float* Sb = S + ((size_t)(b * CCH + seg * SEG)) * EE;
    for (int cc = 0; cc < cin; ++cc) {
      const float* Sc = Sb + (size_t)cc * EE;
      #pragma unroll
      for (int ii = 0; ii < 16; ++ii) run[ii] += Sc[(i0 + ii) * DD + j];
    }
  }

  const float* Kb = Kx + (size_t)bc * LCH * DD;
  const float* Vb = Vx + (size_t)bc * LCH * DD;
  const float* Qb = Qx + (size_t)bc * LCH * DD;
  float kreg[LCH];
  #pragma unroll
  for (int t = 0; t < LCH; ++t) kreg[t] = Kb[t * DD + j];
  float* so = sout + (size_t)bc * LCH * EE + (size_t)i0 * DD + j;
  for (int t = 0; t < LCH; ++t) {
    const float* Vt = Vb + t * DD + i0;   // wave-uniform -> scalar loads
    const float* Qt = Qb + t * DD + i0;
    float kj = kreg[t];
    float y0 = 0.f, y1 = 0.f, y2 = 0.f, y3 = 0.f;
    float* sot = so + (size_t)t * EE;
    #pragma unroll
    for (int ii = 0; ii < 16; ii += 4) {
      run[ii]     += Vt[ii]     * kj; sot[(ii)     * DD] = run[ii];     y0 += run[ii]     * Qt[ii];
      run[ii + 1] += Vt[ii + 1] * kj; sot[(ii + 1) * DD] = run[ii + 1]; y1 += run[ii + 1] * Qt[ii + 1];
      run[ii + 2] += Vt[ii + 2] * kj; sot[(ii + 2) * DD] = run[ii + 2]; y2 += run[ii + 2] * Qt[ii + 2];
      run[ii + 3] += Vt[ii + 3] * kj; sot[(ii + 3) * DD] = run[ii + 3]; y3 += run[ii + 3] * Qt[ii + 3];
    }
    yp[wv][t][j] = (y0 + y1) + (y2 + y3);
  }
  __syncthreads();
  float* yo = y + (size_t)bc * LCH * DD;
  #pragma unroll
  for (int tt = 0; tt < LCH / 4; ++tt) {
    int t = wv * (LCH / 4) + tt;
    yo[t * DD + j] = (yp[0][t][j] + yp[1][t][j]) + (yp[2][t][j] + yp[3][t][j]);
  }
}

extern "C" void kernel_launch(void* const* d_in, const int* in_sizes, int n_in,
                              void* d_out, int out_size, void* d_ws, size_t ws_size,
                              hipStream_t stream) {
  const float* x     = (const float*)d_in[0];
  const float* st0   = (const float*)d_in[1];
  const float* Wk    = (const float*)d_in[2];
  const float* Wq    = (const float*)d_in[3];
  const float* Wv    = (const float*)d_in[4];
  const float* gamma = (const float*)d_in[5];
  const float* beta  = (const float*)d_in[6];

  float* out  = (float*)d_out;                    // fp32 — reference dtype!
  float* yout = out;                              // y [B,T,D] first
  float* sseq = out + (size_t)BB * TT * DD;       // state_seq [B,T,D,D]

  float* ws = (float*)d_ws;
  float* Ko = ws;
  float* Qo = Ko + (size_t)BB * TT * DD;
  float* Vo = Qo + (size_t)BB * TT * DD;
  float* S  = Vo + (size_t)BB * TT * DD;
  float* Z  = S  + (size_t)BB * CCH * EE;

  lnprojcs_k<<<BB * CCH, 256, 0, stream>>>(x, gamma, beta, Wk, Wq, Wv, Ko, Qo, Vo, S);
  segsum_k  <<<BB * NSEG * 16, 256, 0, stream>>>(S, Z);
  scan_k    <<<BB * CCH, 256, 0, stream>>>(Ko, Qo, Vo, S, Z, st0, yout, sseq);
}

// Round 7
// 187.840 us; speedup vs baseline: 1.6674x; 1.1470x over previous
//
#include <hip/hip_runtime.h>

#define BB 8
#define TT 1024
#define FF 512
#define DD 64
#define LCH 16
#define CCH (TT / LCH)
#define SEG 8             // chunks per prefix segment
#define NSEG (CCH / SEG)  // 8 segments per batch
#define EE (DD * DD)
#define NCT 12            // 192 output cols / 16
#define AST 520           // lxh/lxl row stride in halves (512 + 8 pad)
#define CST 196           // lkqv row stride in floats (192 + 4 pad)

typedef short short8 __attribute__((ext_vector_type(8)));
typedef float f32x4 __attribute__((ext_vector_type(4)));

__device__ __forceinline__ float wave_sum64(float v) {
  #pragma unroll
  for (int m = 32; m >= 1; m >>= 1) v += __shfl_xor(v, m, 64);
  return v;
}

__device__ __forceinline__ unsigned short f2bf(float f) {
  unsigned int u = __float_as_uint(f);
  u += 0x7FFFu + ((u >> 16) & 1u);      // RNE
  return (unsigned short)(u >> 16);
}
__device__ __forceinline__ float bf2f(unsigned short h) {
  return __uint_as_float(((unsigned int)h) << 16);
}

// ------- Kernel 0: weight prep -> fragment-ordered bf16 hi/lo -----------
// Layout: Wh/Wl[((ct*16 + kk)*64 + lane)*8 + j], k = kk*32 + 8*(lane>>4)+j,
// col = ct*16 + (lane&15). Same k-slot convention as the A-side fragments.
__global__ __launch_bounds__(64) void wprep_k(
    const float* __restrict__ Wk, const float* __restrict__ Wq,
    const float* __restrict__ Wv,
    unsigned short* __restrict__ Wh, unsigned short* __restrict__ Wl) {
  int blk = blockIdx.x;           // = ct*16 + kk
  int ct = blk >> 4, kk = blk & 15;
  int lane = threadIdx.x;
  int p = ct >> 2;
  const float* Wp = (p == 0) ? Wk : (p == 1) ? Wq : Wv;
  int d = ((ct & 3) << 4) + (lane & 15);
  int k0 = (kk << 5) + ((lane >> 4) << 3);
  size_t o = ((size_t)blk * 64 + lane) * 8;
  #pragma unroll
  for (int j = 0; j < 8; ++j) {
    float w = Wp[(size_t)(k0 + j) * DD + d];
    unsigned short h = f2bf(w);
    float rem = w - bf2f(h);
    Wh[o + j] = h;
    Wl[o + j] = f2bf(rem);
  }
}

// ------- Kernel 1: LN + MFMA KQV projection + chunk outer sum ----------
// Block = one 16-token chunk, 256 thr. LDS 33 KB -> 4 blocks/CU.
//  A/B: LN from global, write xh/xl bf16 to padded LDS (conflict-free frags)
//  C: 16x16x32 bf16 MFMA, split-precision (hh + hl + lh + ll), wave owns
//     3 col-tiles of the 16x192 combined K|Q|V output
//  D: C-tiles -> LDS overlay; relu+sumnorm epilogue; store K/Q/V
//  F: chunk outer-product sum S from LDS-resident K,V
__global__ __launch_bounds__(256) void lnprojcs_k(
    const float* __restrict__ x,
    const float* __restrict__ gamma, const float* __restrict__ beta,
    const unsigned short* __restrict__ Wh, const unsigned short* __restrict__ Wl,
    float* __restrict__ Ko, float* __restrict__ Qo, float* __restrict__ Vo,
    float* __restrict__ S) {
  __shared__ __align__(16) char smem[2 * LCH * AST * 2];   // 33280 B
  unsigned short* lxh = (unsigned short*)smem;
  unsigned short* lxl = lxh + LCH * AST;
  float* lkqv = (float*)smem;      // overlay, live after phase C

  const int tid = threadIdx.x;
  const int wv = tid >> 6, lane = tid & 63;
  const int bc = blockIdx.x;
  const size_t row0 = (size_t)bc * LCH;

  { // A/B: LayerNorm straight from global; write bf16 hi/lo fragments
    float g[8], bt[8];
    #pragma unroll
    for (int k = 0; k < 8; ++k) {
      g[k]  = gamma[lane + 64 * k];
      bt[k] = beta[lane + 64 * k];
    }
    #pragma unroll
    for (int rr = 0; rr < 4; ++rr) {
      int r = wv * 4 + rr;
      const float* xr = x + (row0 + r) * FF;
      float v[8];
      float s = 0.f, ss = 0.f;
      #pragma unroll
      for (int k = 0; k < 8; ++k) {
        v[k] = xr[lane + 64 * k];
        s += v[k]; ss += v[k] * v[k];
      }
      s = wave_sum64(s); ss = wave_sum64(ss);
      float m = s * (1.f / FF);
      float var = ss * (1.f / FF) - m * m;
      float rs = rsqrtf(var + 1e-5f);
      #pragma unroll
      for (int k = 0; k < 8; ++k) {
        float xv = (v[k] - m) * rs * g[k] + bt[k];
        unsigned short h = f2bf(xv);
        float rem = xv - bf2f(h);
        lxh[r * AST + lane + 64 * k] = h;
        lxl[r * AST + lane + 64 * k] = f2bf(rem);
      }
    }
  }
  __syncthreads();

  // C: MFMA. Wave wv owns col-tiles ct = wv*3 .. wv*3+2.
  f32x4 acc0 = {0.f, 0.f, 0.f, 0.f};
  f32x4 acc1 = {0.f, 0.f, 0.f, 0.f};
  f32x4 acc2 = {0.f, 0.f, 0.f, 0.f};
  {
    const int arow = lane & 15, agrp = lane >> 4;
    const unsigned short* abase = lxh + arow * AST + agrp * 8;
    const size_t wbase = (((size_t)(wv * 3) * 16) * 64 + lane) * 8;
    for (int kk = 0; kk < 16; ++kk) {
      const unsigned short* ap = abase + kk * 32;
      short8 ah = *(const short8*)ap;
      short8 al = *(const short8*)(ap + LCH * AST);
      size_t wo = wbase + (size_t)kk * 64 * 8;
      short8 bh0 = *(const short8*)(Wh + wo);
      short8 bl0 = *(const short8*)(Wl + wo);
      short8 bh1 = *(const short8*)(Wh + wo + 8192);
      short8 bl1 = *(const short8*)(Wl + wo + 8192);
      short8 bh2 = *(const short8*)(Wh + wo + 16384);
      short8 bl2 = *(const short8*)(Wl + wo + 16384);
      acc0 = __builtin_amdgcn_mfma_f32_16x16x32_bf16(ah, bh0, acc0, 0, 0, 0);
      acc0 = __builtin_amdgcn_mfma_f32_16x16x32_bf16(ah, bl0, acc0, 0, 0, 0);
      acc0 = __builtin_amdgcn_mfma_f32_16x16x32_bf16(al, bh0, acc0, 0, 0, 0);
      acc0 = __builtin_amdgcn_mfma_f32_16x16x32_bf16(al, bl0, acc0, 0, 0, 0);
      acc1 = __builtin_amdgcn_mfma_f32_16x16x32_bf16(ah, bh1, acc1, 0, 0, 0);
      acc1 = __builtin_amdgcn_mfma_f32_16x16x32_bf16(ah, bl1, acc1, 0, 0, 0);
      acc1 = __builtin_amdgcn_mfma_f32_16x16x32_bf16(al, bh1, acc1, 0, 0, 0);
      acc1 = __builtin_amdgcn_mfma_f32_16x16x32_bf16(al, bl1, acc1, 0, 0, 0);
      acc2 = __builtin_amdgcn_mfma_f32_16x16x32_bf16(ah, bh2, acc2, 0, 0, 0);
      acc2 = __builtin_amdgcn_mfma_f32_16x16x32_bf16(ah, bl2, acc2, 0, 0, 0);
      acc2 = __builtin_amdgcn_mfma_f32_16x16x32_bf16(al, bh2, acc2, 0, 0, 0);
      acc2 = __builtin_amdgcn_mfma_f32_16x16x32_bf16(al, bl2, acc2, 0, 0, 0);
    }
  }
  __syncthreads();   // lxh/lxl dead -> lkqv overlay

  { // C-tiles to LDS: C/D layout col=lane&15, row=(lane>>4)*4+reg [m89]
    const int ccol = lane & 15, crow0 = (lane >> 4) << 2;
    const int n0 = (wv * 3) << 4;
    #pragma unroll
    for (int reg = 0; reg < 4; ++reg) {
      lkqv[(crow0 + reg) * CST + n0 +  0 + ccol] = acc0[reg];
      lkqv[(crow0 + reg) * CST + n0 + 16 + ccol] = acc1[reg];
      lkqv[(crow0 + reg) * CST + n0 + 32 + ccol] = acc2[reg];
    }
  }
  __syncthreads();

  // E: epilogue — 48 (row,proj) pairs, 12 per wave; lane = d
  #pragma unroll
  for (int i = 0; i < 12; ++i) {
    int pid = wv * 12 + i;
    int r = pid / 3, p = pid - r * 3;
    float val = lkqv[r * CST + p * 64 + lane];
    if (p < 2) {
      val = fmaxf(val, 0.f);
      float sm = wave_sum64(val);
      val = val / (1e-5f + sm);
    }
    float* outp = (p == 0) ? Ko : (p == 1) ? Qo : Vo;
    outp[(row0 + r) * DD + lane] = val;
    lkqv[r * CST + p * 64 + lane] = val;   // normalized K (and Q), V for F
  }
  __syncthreads();

  // F: chunk outer-product sum -> S  (K at col 0, V at col 128 in lkqv)
  {
    const int j = lane, s0i = wv << 4;
    float a2[16];
    #pragma unroll
    for (int ii = 0; ii < 16; ++ii) a2[ii] = 0.f;
    #pragma unroll
    for (int t = 0; t < LCH; ++t) {
      float kj = lkqv[t * CST + j];
      #pragma unroll
      for (int ii = 0; ii < 16; ++ii)
        a2[ii] += lkqv[t * CST + 128 + s0i + ii] * kj;
    }
    float* Sp = S + (size_t)bc * EE;
    #pragma unroll
    for (int ii = 0; ii < 16; ++ii) Sp[(s0i + ii) * DD + j] = a2[ii];
  }
}

// ------- Kernel 2: segment sums Z[b][seg] = sum of 8 chunk S tiles ------
__global__ __launch_bounds__(256) void segsum_k(const float* __restrict__ S,
                                                float* __restrict__ Z) {
  int blk = blockIdx.x;
  int b = blk >> 7;
  int seg = (blk >> 4) & 7;
  int e = ((blk & 15) << 8) + threadIdx.x;
  const float* Sb = S + ((size_t)(b * CCH + seg * SEG)) * EE + e;
  float sv[SEG];
  #pragma unroll
  for (int c = 0; c < SEG; ++c) sv[c] = Sb[(size_t)c * EE];
  float acc = 0.f;
  #pragma unroll
  for (int c = 0; c < SEG; ++c) acc += sv[c];
  Z[((size_t)(b * NSEG + seg)) * EE + e] = acc;
}

// ------- Kernel 3: seg-base + in-segment exclusive scan -> P ------------
__global__ __launch_bounds__(256) void segscan_k(const float* __restrict__ S,
                                                 const float* __restrict__ Z,
                                                 const float* __restrict__ st0,
                                                 float* __restrict__ P) {
  int blk = blockIdx.x;
  int b = blk >> 7;
  int seg = (blk >> 4) & 7;
  int e = ((blk & 15) << 8) + threadIdx.x;
  float run = st0[(size_t)b * EE + e];
  const float* Zb = Z + (size_t)b * NSEG * EE + e;
  float zv[NSEG - 1];
  #pragma unroll
  for (int s = 0; s < NSEG - 1; ++s) zv[s] = Zb[(size_t)s * EE];
  #pragma unroll
  for (int s = 0; s < NSEG - 1; ++s) if (s < seg) run += zv[s];
  const float* Sb = S + ((size_t)(b * CCH + seg * SEG)) * EE + e;
  float* Pb = P + ((size_t)(b * CCH + seg * SEG)) * EE + e;
  float sv[SEG];
  #pragma unroll
  for (int c = 0; c < SEG; ++c) sv[c] = Sb[(size_t)c * EE];
  #pragma unroll
  for (int c = 0; c < SEG; ++c) {
    Pb[(size_t)c * EE] = run;
    run += sv[c];
  }
}

// ------- Kernel 4: in-chunk scan + y, 4-wave i-split --------------------
__global__ __launch_bounds__(256) void scan_k(const float* __restrict__ Kx,
                     const float* __restrict__ Qx, const float* __restrict__ Vx,
                     const float* __restrict__ P,
                     float* __restrict__ y, float* __restrict__ sout) {
  int bc = blockIdx.x, tid = threadIdx.x;
  int wv = tid >> 6, j = tid & 63;
  int i0 = wv * 16;
  __shared__ float yp[4][LCH][DD];   // 16 KB
  float Sr[16];
  const float* Pp = P + (size_t)bc * EE;
  #pragma unroll
  for (int ii = 0; ii < 16; ++ii) Sr[ii] = Pp[(i0 + ii) * DD + j];
  const float* Kb = Kx + (size_t)bc * LCH * DD;
  const float* Vb = Vx + (size_t)bc * LCH * DD;
  const float* Qb = Qx + (size_t)bc * LCH * DD;
  float kreg[LCH];
  #pragma unroll
  for (int t = 0; t < LCH; ++t) kreg[t] = Kb[t * DD + j];
  float* so = sout + (size_t)bc * LCH * EE + (size_t)i0 * DD + j;
  for (int t = 0; t < LCH; ++t) {
    const float* Vt = Vb + t * DD + i0;   // wave-uniform -> scalar loads
    const float* Qt = Qb + t * DD + i0;
    float kj = kreg[t];
    float y0 = 0.f, y1 = 0.f, y2 = 0.f, y3 = 0.f;
    float* sot = so + (size_t)t * EE;
    #pragma unroll
    for (int ii = 0; ii < 16; ii += 4) {
      Sr[ii]     += Vt[ii]     * kj; sot[(ii)     * DD] = Sr[ii];     y0 += Sr[ii]     * Qt[ii];
      Sr[ii + 1] += Vt[ii + 1] * kj; sot[(ii + 1) * DD] = Sr[ii + 1]; y1 += Sr[ii + 1] * Qt[ii + 1];
      Sr[ii + 2] += Vt[ii + 2] * kj; sot[(ii + 2) * DD] = Sr[ii + 2]; y2 += Sr[ii + 2] * Qt[ii + 2];
      Sr[ii + 3] += Vt[ii + 3] * kj; sot[(ii + 3) * DD] = Sr[ii + 3]; y3 += Sr[ii + 3] * Qt[ii + 3];
    }
    yp[wv][t][j] = (y0 + y1) + (y2 + y3);
  }
  __syncthreads();
  float* yo = y + (size_t)bc * LCH * DD;
  #pragma unroll
  for (int tt = 0; tt < LCH / 4; ++tt) {
    int t = wv * (LCH / 4) + tt;
    yo[t * DD + j] = (yp[0][t][j] + yp[1][t][j]) + (yp[2][t][j] + yp[3][t][j]);
  }
}

extern "C" void kernel_launch(void* const* d_in, const int* in_sizes, int n_in,
                              void* d_out, int out_size, void* d_ws, size_t ws_size,
                              hipStream_t stream) {
  const float* x     = (const float*)d_in[0];
  const float* st0   = (const float*)d_in[1];
  const float* Wk    = (const float*)d_in[2];
  const float* Wq    = (const float*)d_in[3];
  const float* Wv    = (const float*)d_in[4];
  const float* gamma = (const float*)d_in[5];
  const float* beta  = (const float*)d_in[6];

  float* out  = (float*)d_out;                    // fp32 — reference dtype!
  float* yout = out;                              // y [B,T,D] first
  float* sseq = out + (size_t)BB * TT * DD;       // state_seq [B,T,D,D]

  float* ws = (float*)d_ws;
  float* Ko = ws;
  float* Qo = Ko + (size_t)BB * TT * DD;
  float* Vo = Qo + (size_t)BB * TT * DD;
  float* S  = Vo + (size_t)BB * TT * DD;
  float* P  = S  + (size_t)BB * CCH * EE;
  float* Z  = P  + (size_t)BB * CCH * EE;
  unsigned short* Wh = (unsigned short*)(Z + (size_t)BB * NSEG * EE);
  unsigned short* Wl = Wh + (size_t)NCT * 16 * 64 * 8;

  wprep_k   <<<NCT * 16, 64, 0, stream>>>(Wk, Wq, Wv, Wh, Wl);
  lnprojcs_k<<<BB * CCH, 256, 0, stream>>>(x, gamma, beta, Wh, Wl, Ko, Qo, Vo, S);
  segsum_k  <<<BB * NSEG * 16, 256, 0, stream>>>(S, Z);
  segscan_k <<<BB * NSEG * 16, 256, 0, stream>>>(S, Z, st0, P);
  scan_k    <<<BB * CCH, 256, 0, stream>>>(Ko, Qo, Vo, P, yout, sseq);
}